// Round 3
// baseline (155.245 us; speedup 1.0000x reference)
//
#include <hip/hip_runtime.h>
#include <math.h>

#define BATCH 16
#define KVH 8
#define QM 8
#define NH 64
#define HD 128
#define CACHE 8192
#define WIN 4096
#define TOTAL (CACHE + 1)
#define PSTART (TOTAL - WIN)        // 4097: first unmasked position
#define KSTRIDE (KVH * HD)          // 1024 floats per cache row
#define REC_FLOATS (QM * (HD + 2))  // record: m[8], l[8], acc[8][128]
#define SM_SCALE 0.08838834764831845f

// ---------------------------------------------------------------------------
// Kernel 1: wave-independent streaming flash attention, no K/V LDS staging.
// grid = (NSPLIT, KVH, BATCH), block = 256 (4 independent waves).
// Lane layout: dp = lane&31 owns dims d0=4*dp..d0+3 of ALL 8 heads.
//   hi = lane>>5 selects which of the step's 2 positions this half handles.
//   Own head for softmax state: hm = dp&7 (4 replicas per half).
// Per step: 1 coalesced float4 K load + 1 V load per lane; 8-head partial
// dots folded across 32 lanes (shfl masks 1,2,4 fold heads, 8,16 butterfly);
// per-lane scalar online softmax; PV via 8 shuffle weight broadcasts.
// ---------------------------------------------------------------------------

template <bool EDGE>
__device__ __forceinline__ void run_span(
    const float4 q4[8], float4 acc[8], float& mrun, float& lrun,
    const float* kc, const float* vc, const float* kn, const float* vn,
    int pb, int nstep, int ln) {

    auto loadK = [&](int p) -> float4 {
        const float* src = (!EDGE || p < CACHE) ? (kc + (size_t)p * KSTRIDE) : kn;
        return *reinterpret_cast<const float4*>(src);
    };
    auto loadV = [&](int p) -> float4 {
        const float* src = (!EDGE || p < CACHE) ? (vc + (size_t)p * KSTRIDE) : vn;
        return *reinterpret_cast<const float4*>(src);
    };

    const int dp = ln & 31;
    float4 k4 = loadK(pb);
    float4 v4 = loadV(pb);

    for (int j = 0; j < nstep; ++j) {
        float4 kcur = k4, vcur = v4;
        if (j + 1 < nstep) {           // prefetch next step
            int pn = pb + 2 * (j + 1);
            k4 = loadK(pn);
            v4 = loadV(pn);
        }

        // partial dots for all 8 heads over this lane's 4 dims
        float part[8];
        #pragma unroll
        for (int h = 0; h < 8; ++h)
            part[h] = q4[h].x * kcur.x + q4[h].y * kcur.y +
                      q4[h].z * kcur.z + q4[h].w * kcur.w;

        // fold head-bit0 via lane-bit0 (8 -> 4 values)
        float f4[4];
        {
            const bool s1 = dp & 1;
            #pragma unroll
            for (int i = 0; i < 4; ++i) {
                float send = s1 ? part[2*i]   : part[2*i+1];
                float keep = s1 ? part[2*i+1] : part[2*i];
                f4[i] = keep + __shfl_xor(send, 1);
            }
        }
        // fold head-bit1 via lane-bit1 (4 -> 2)
        float f2[2];
        {
            const bool s2 = dp & 2;
            #pragma unroll
            for (int i = 0; i < 2; ++i) {
                float send = s2 ? f4[2*i]   : f4[2*i+1];
                float keep = s2 ? f4[2*i+1] : f4[2*i];
                f2[i] = keep + __shfl_xor(send, 2);
            }
        }
        // fold head-bit2 via lane-bit2 (2 -> 1)
        float s;
        {
            const bool s4 = dp & 4;
            float send = s4 ? f2[0] : f2[1];
            float keep = s4 ? f2[1] : f2[0];
            s = keep + __shfl_xor(send, 4);
        }
        // butterfly over remaining lane bits -> full dot, replicated
        s += __shfl_xor(s, 8);
        s += __shfl_xor(s, 16);
        // s = score(head = dp&7, position = pb + 2j) for this half-wave

        // deferred-max online softmax (rescale only when max grows > 8)
        if (__any(s > mrun + 8.0f)) {
            float mn = fmaxf(mrun, s);
            float rs = __expf(mrun - mn);   // 0 on first step (mrun = -inf)
            mrun = mn;
            lrun *= rs;
            #pragma unroll
            for (int h = 0; h < 8; ++h) {
                float rh = __shfl(rs, (ln & 0x20) | h);
                acc[h].x *= rh; acc[h].y *= rh; acc[h].z *= rh; acc[h].w *= rh;
            }
        }
        float e = __expf(s - mrun);
        lrun += e;
        #pragma unroll
        for (int h = 0; h < 8; ++h) {
            float wh = __shfl(e, (ln & 0x20) | h);
            acc[h].x += wh * vcur.x; acc[h].y += wh * vcur.y;
            acc[h].z += wh * vcur.z; acc[h].w += wh * vcur.w;
        }
    }
}

template <int NSPLIT>
__global__ __launch_bounds__(256, 4)
void attn_partial(const float* __restrict__ Q,
                  const float* __restrict__ Knew,
                  const float* __restrict__ Vnew,
                  const float* __restrict__ Kc,
                  const float* __restrict__ Vc,
                  float* __restrict__ ws) {
    constexpr int SPAN  = WIN / NSPLIT;   // positions per block
    constexpr int WSPAN = SPAN / 4;       // positions per wave
    constexpr int NSTEP = WSPAN / 2;      // steps (2 positions/step)

    const int c   = blockIdx.x;
    const int kvh = blockIdx.y;
    const int b   = blockIdx.z;
    const int t   = threadIdx.x;
    const int wid = t >> 6;
    const int ln  = t & 63;
    const int dp  = ln & 31;
    const int d0  = dp * 4;

    // Q fragment in registers (pre-scaled)
    float4 q4[8];
    {
        const float* qp = Q + ((size_t)b * NH + (size_t)kvh * QM) * HD + d0;
        #pragma unroll
        for (int h = 0; h < 8; ++h) {
            float4 v = *reinterpret_cast<const float4*>(qp + h * HD);
            q4[h] = make_float4(v.x * SM_SCALE, v.y * SM_SCALE,
                                v.z * SM_SCALE, v.w * SM_SCALE);
        }
    }

    const int hi = ln >> 5;
    const int pb = PSTART + c * SPAN + wid * WSPAN + hi;  // lane's first position

    const float* kc = Kc + (size_t)b * CACHE * KSTRIDE + (size_t)kvh * HD + d0;
    const float* vc = Vc + (size_t)b * CACHE * KSTRIDE + (size_t)kvh * HD + d0;
    const float* kn = Knew + (size_t)b * KSTRIDE + (size_t)kvh * HD + d0;
    const float* vn = Vnew + (size_t)b * KSTRIDE + (size_t)kvh * HD + d0;

    float4 acc[8];
    #pragma unroll
    for (int h = 0; h < 8; ++h) acc[h] = make_float4(0.f, 0.f, 0.f, 0.f);
    float mrun = -INFINITY;
    float lrun = 0.f;

    // only the span containing position CACHE needs the edge check
    if (pb + 2 * NSTEP - 2 >= CACHE)
        run_span<true >(q4, acc, mrun, lrun, kc, vc, kn, vn, pb, NSTEP, ln);
    else
        run_span<false>(q4, acc, mrun, lrun, kc, vc, kn, vn, pb, NSTEP, ln);

    // ---- merge the two hi-halves (independent softmax states) ----
    // NOTE: acc[h] must be scaled by head h's factors, fetched via shuffle
    // from lane (half*32 + h) — NOT by this lane's own-head f/fo.
    {
        float mo = __shfl_xor(mrun, 32);
        float lo = __shfl_xor(lrun, 32);
        float M  = fmaxf(mrun, mo);
        float f  = __expf(mrun - M);   // own-half factor, head dp&7
        float fo = __expf(mo - M);     // other-half factor, head dp&7
        lrun = lrun * f + lo * fo;
        mrun = M;
        #pragma unroll
        for (int h = 0; h < 8; ++h) {
            float fh  = __shfl(f,  (ln & 0x20) | h);
            float foh = __shfl(fo, (ln & 0x20) | h);
            float ax = __shfl_xor(acc[h].x, 32);
            float ay = __shfl_xor(acc[h].y, 32);
            float az = __shfl_xor(acc[h].z, 32);
            float aw = __shfl_xor(acc[h].w, 32);
            acc[h].x = acc[h].x * fh + ax * foh;
            acc[h].y = acc[h].y * fh + ay * foh;
            acc[h].z = acc[h].z * fh + az * foh;
            acc[h].w = acc[h].w * fh + aw * foh;
        }
    }

    // ---- block merge of the 4 waves via LDS ----
    __shared__ float  sm_m[4][8];
    __shared__ float  sm_l[4][8];
    __shared__ float4 sm_a[4][8][32];

    if (ln < 32) {
        if (dp < 8) { sm_m[wid][dp] = mrun; sm_l[wid][dp] = lrun; }
        #pragma unroll
        for (int h = 0; h < 8; ++h) sm_a[wid][h][dp] = acc[h];
    }
    __syncthreads();

    const int h  = t >> 5;   // head 0..7
    const int dd = t & 31;   // dim quad
    float mv[4];
    float M = -INFINITY;
    #pragma unroll
    for (int i = 0; i < 4; ++i) { mv[i] = sm_m[i][h]; M = fmaxf(M, mv[i]); }
    float lt = 0.f;
    float4 o = make_float4(0.f, 0.f, 0.f, 0.f);
    #pragma unroll
    for (int i = 0; i < 4; ++i) {
        float f = __expf(mv[i] - M);
        lt += sm_l[i][h] * f;
        float4 a = sm_a[i][h][dd];
        o.x += a.x * f; o.y += a.y * f; o.z += a.z * f; o.w += a.w * f;
    }
    float* rec = ws + (size_t)((b * KVH + kvh) * NSPLIT + c) * REC_FLOATS;
    if (dd == 0) { rec[h] = M; rec[QM + h] = lt; }
    *reinterpret_cast<float4*>(rec + 2 * QM + h * HD + 4 * dd) = o;
}

// ---------------------------------------------------------------------------
// Kernel 2: combine chunk partials + sink logit. grid = (KVH, BATCH).
// ---------------------------------------------------------------------------
template <int NC>
__global__ __launch_bounds__(256)
void attn_combine(const float* __restrict__ ws,
                  const float* __restrict__ sinks,
                  float* __restrict__ out) {
    const int kvh = blockIdx.x;
    const int b   = blockIdx.y;
    const int t   = threadIdx.x;
    const int h   = t >> 5;
    const int lp  = t & 31;

    const float* base = ws + (size_t)((b * KVH + kvh) * NC) * REC_FLOATS;
    const float sk = sinks[kvh * QM + h];

    float m[NC], l[NC];
    float M = sk;
    #pragma unroll
    for (int c = 0; c < NC; ++c) {
        m[c] = base[(size_t)c * REC_FLOATS + h];
        l[c] = base[(size_t)c * REC_FLOATS + QM + h];
        M = fmaxf(M, m[c]);
    }
    float denom = __expf(sk - M);   // sink contributes to denominator only
    float wgt[NC];
    #pragma unroll
    for (int c = 0; c < NC; ++c) {
        wgt[c] = __expf(m[c] - M);
        denom += wgt[c] * l[c];
    }
    float inv = 1.f / denom;

    float4 o = make_float4(0.f, 0.f, 0.f, 0.f);
    #pragma unroll
    for (int c = 0; c < NC; ++c) {
        const float* accp = base + (size_t)c * REC_FLOATS + 2 * QM + h * HD;
        float4 a = *reinterpret_cast<const float4*>(accp + 4 * lp);
        o.x += wgt[c] * a.x; o.y += wgt[c] * a.y;
        o.z += wgt[c] * a.z; o.w += wgt[c] * a.w;
    }
    float* op = out + (size_t)b * NH * HD + (size_t)(kvh * QM + h) * HD;
    float4 r = make_float4(o.x * inv, o.y * inv, o.z * inv, o.w * inv);
    *reinterpret_cast<float4*>(op + 4 * lp) = r;
}

// ---------------------------------------------------------------------------
template <int NSPLIT>
static void launch_nc(const float* Q, const float* K, const float* V,
                      const float* Kc, const float* Vc, const float* sinks,
                      float* out, float* ws, hipStream_t stream) {
    dim3 g1(NSPLIT, KVH, BATCH);
    attn_partial<NSPLIT><<<g1, 256, 0, stream>>>(Q, K, V, Kc, Vc, ws);
    dim3 g2(KVH, BATCH);
    attn_combine<NSPLIT><<<g2, 256, 0, stream>>>(ws, sinks, out);
}

extern "C" void kernel_launch(void* const* d_in, const int* in_sizes, int n_in,
                              void* d_out, int out_size, void* d_ws, size_t ws_size,
                              hipStream_t stream) {
    const float* Q     = (const float*)d_in[0];
    const float* K     = (const float*)d_in[1];
    const float* V     = (const float*)d_in[2];
    const float* Kc    = (const float*)d_in[3];
    const float* Vc    = (const float*)d_in[4];
    const float* sinks = (const float*)d_in[5];
    float* out = (float*)d_out;
    float* ws  = (float*)d_ws;

    auto need = [](int nc) {
        return (size_t)BATCH * KVH * nc * REC_FLOATS * sizeof(float);
    };
    if (ws_size >= need(16))     launch_nc<16>(Q, K, V, Kc, Vc, sinks, out, ws, stream);
    else if (ws_size >= need(8)) launch_nc<8>(Q, K, V, Kc, Vc, sinks, out, ws, stream);
    else if (ws_size >= need(4)) launch_nc<4>(Q, K, V, Kc, Vc, sinks, out, ws, stream);
    else                         launch_nc<2>(Q, K, V, Kc, Vc, sinks, out, ws, stream);
}

// Round 4
// 122.020 us; speedup vs baseline: 1.2723x; 1.2723x over previous
//
#include <hip/hip_runtime.h>
#include <math.h>

#define BATCH 16
#define KVH 8
#define QM 8
#define NH 64
#define HD 128
#define CACHE 8192
#define WIN 4096
#define PSTART (CACHE + 1 - WIN)       // 4097: first unmasked position
#define KSTRIDE (KVH * HD)             // 1024 floats = 4 KB per cache row
#define REC_FLOATS (2 * QM + QM * HD)  // m[8], l[8], acc[8][128] = 1040
#define SM_SCALE 0.08838834764831845f

// broadcast lane h (imm = h<<5) to all lanes within each 32-lane half
#define BCAST(x, imm) __int_as_float(__builtin_amdgcn_ds_swizzle(__float_as_int(x), (imm)))

#define SCALE_ACC(h, rr) { acc[h].x *= rr; acc[h].y *= rr; acc[h].z *= rr; acc[h].w *= rr; }
#define PV_ACC(h, ww)    { acc[h].x += ww*vc4.x; acc[h].y += ww*vc4.y; acc[h].z += ww*vc4.z; acc[h].w += ww*vc4.w; }

// ---------------------------------------------------------------------------
// Kernel 1: block = (batch b, span c), 256 threads cover the FULL 4 KB K/V row
// per position (thread t -> column t*4 = kvh t>>5, dims 4*(t&31)).  Fully
// sequential 4 KB-row streams from HBM; no LDS storage; no barriers.
// Each 32-lane group is an independent kvh unit: register Q (8 heads x 4 dims),
// fold-network dots, per-lane deferred-max online softmax (own head = lane&7),
// ds_swizzle weight broadcast, register PV accumulate.
// ---------------------------------------------------------------------------
template <int NSPLIT, bool EDGE>
__device__ __forceinline__ void attn_body(
    int c, int b, int t,
    const float* __restrict__ Q, const float* __restrict__ Knew,
    const float* __restrict__ Vnew, const float* __restrict__ Kc,
    const float* __restrict__ Vc, float* __restrict__ ws) {
    constexpr int SPAN = WIN / NSPLIT;
    static_assert(SPAN % 2 == 0, "unroll-2");
    const int g  = t >> 5;     // kvh group
    const int dp = t & 31;     // lane in group
    const int pb = PSTART + c * SPAN;

    // Q fragment: 8 q-heads of kvh g, this lane's 4 dims (pre-scaled)
    float4 q4[8];
    {
        const float* qp = Q + ((size_t)b * NH + (size_t)g * QM) * HD + dp * 4;
        #pragma unroll
        for (int h = 0; h < 8; ++h) {
            float4 v = *reinterpret_cast<const float4*>(qp + h * HD);
            q4[h] = make_float4(v.x * SM_SCALE, v.y * SM_SCALE,
                                v.z * SM_SCALE, v.w * SM_SCALE);
        }
    }

    const float* kb_ = Kc + ((size_t)b * CACHE + pb) * KSTRIDE + t * 4;
    const float* vb_ = Vc + ((size_t)b * CACHE + pb) * KSTRIDE + t * 4;
    const float* kn_ = Knew + (size_t)b * KSTRIDE + t * 4;
    const float* vn_ = Vnew + (size_t)b * KSTRIDE + t * 4;

    auto LK = [&](int j) -> float4 {
        const float* a = kb_ + (size_t)j * KSTRIDE;
        if (EDGE && (pb + j >= CACHE)) a = kn_;   // folds away for !EDGE
        return *reinterpret_cast<const float4*>(a);
    };
    auto LV = [&](int j) -> float4 {
        const float* a = vb_ + (size_t)j * KSTRIDE;
        if (EDGE && (pb + j >= CACHE)) a = vn_;
        return *reinterpret_cast<const float4*>(a);
    };

    float4 acc[8];
    #pragma unroll
    for (int h = 0; h < 8; ++h) acc[h] = make_float4(0.f, 0.f, 0.f, 0.f);
    float mrun = -INFINITY, lrun = 0.f;

    auto STEP = [&](float4 kc4, float4 vc4) {
        // partial dots: 8 heads x this lane's 4 dims
        float p0 = q4[0].x*kc4.x + q4[0].y*kc4.y + q4[0].z*kc4.z + q4[0].w*kc4.w;
        float p1 = q4[1].x*kc4.x + q4[1].y*kc4.y + q4[1].z*kc4.z + q4[1].w*kc4.w;
        float p2 = q4[2].x*kc4.x + q4[2].y*kc4.y + q4[2].z*kc4.z + q4[2].w*kc4.w;
        float p3 = q4[3].x*kc4.x + q4[3].y*kc4.y + q4[3].z*kc4.z + q4[3].w*kc4.w;
        float p4 = q4[4].x*kc4.x + q4[4].y*kc4.y + q4[4].z*kc4.z + q4[4].w*kc4.w;
        float p5 = q4[5].x*kc4.x + q4[5].y*kc4.y + q4[5].z*kc4.z + q4[5].w*kc4.w;
        float p6 = q4[6].x*kc4.x + q4[6].y*kc4.y + q4[6].z*kc4.z + q4[6].w*kc4.w;
        float p7 = q4[7].x*kc4.x + q4[7].y*kc4.y + q4[7].z*kc4.z + q4[7].w*kc4.w;
        // fold head-bit0 via lane-bit0
        const bool s1 = dp & 1;
        float a0 = (s1?p1:p0) + __shfl_xor((s1?p0:p1), 1);
        float a1 = (s1?p3:p2) + __shfl_xor((s1?p2:p3), 1);
        float a2 = (s1?p5:p4) + __shfl_xor((s1?p4:p5), 1);
        float a3 = (s1?p7:p6) + __shfl_xor((s1?p6:p7), 1);
        // fold head-bit1 via lane-bit1
        const bool s2 = dp & 2;
        float b0 = (s2?a1:a0) + __shfl_xor((s2?a0:a1), 2);
        float b1 = (s2?a3:a2) + __shfl_xor((s2?a2:a3), 2);
        // fold head-bit2 via lane-bit2
        const bool s4 = dp & 4;
        float s = (s4?b1:b0) + __shfl_xor((s4?b0:b1), 4);
        // spatial butterfly -> full 128-dim dot, head = dp&7, replicated x4
        s += __shfl_xor(s, 8);
        s += __shfl_xor(s, 16);

        // deferred-max online softmax (rescale only when max grows > 8)
        if (__any(s > mrun + 8.0f)) {
            float mn = fmaxf(mrun, s);
            float rs = __expf(mrun - mn);   // 0 on first step
            mrun = mn; lrun *= rs;
            float r0 = BCAST(rs, 0x00); SCALE_ACC(0, r0);
            float r1 = BCAST(rs, 0x20); SCALE_ACC(1, r1);
            float r2 = BCAST(rs, 0x40); SCALE_ACC(2, r2);
            float r3 = BCAST(rs, 0x60); SCALE_ACC(3, r3);
            float r4 = BCAST(rs, 0x80); SCALE_ACC(4, r4);
            float r5 = BCAST(rs, 0xA0); SCALE_ACC(5, r5);
            float r6 = BCAST(rs, 0xC0); SCALE_ACC(6, r6);
            float r7 = BCAST(rs, 0xE0); SCALE_ACC(7, r7);
        }
        float e = __expf(s - mrun);
        lrun += e;
        float w0 = BCAST(e, 0x00); PV_ACC(0, w0);
        float w1 = BCAST(e, 0x20); PV_ACC(1, w1);
        float w2 = BCAST(e, 0x40); PV_ACC(2, w2);
        float w3 = BCAST(e, 0x60); PV_ACC(3, w3);
        float w4 = BCAST(e, 0x80); PV_ACC(4, w4);
        float w5 = BCAST(e, 0xA0); PV_ACC(5, w5);
        float w6 = BCAST(e, 0xC0); PV_ACC(6, w6);
        float w7 = BCAST(e, 0xE0); PV_ACC(7, w7);
    };

    // depth-2 prefetch, unroll-2 (statically-named buffers)
    float4 ka = LK(0), va = LV(0), kb4 = LK(1), vb4 = LV(1);
    for (int j = 0; j < SPAN; j += 2) {
        float4 k0 = ka, v0 = va;
        ka = LK(j + 2); va = LV(j + 2);     // over-read past span is in-bounds
        STEP(k0, v0);
        float4 k1 = kb4, v1 = vb4;
        kb4 = LK(j + 3); vb4 = LV(j + 3);
        STEP(k1, v1);
    }

    // write partial record for (b, kvh=g, chunk=c); lanes 0..7 hold heads 0..7
    float* rec = ws + ((size_t)(b * KVH + g) * NSPLIT + c) * REC_FLOATS;
    if (dp < 8) { rec[dp] = mrun; rec[QM + dp] = lrun; }
    #pragma unroll
    for (int h = 0; h < 8; ++h)
        *reinterpret_cast<float4*>(rec + 2 * QM + h * HD + dp * 4) = acc[h];
}

template <int NSPLIT>
__global__ __launch_bounds__(256, 4)
void attn_partial(const float* __restrict__ Q, const float* __restrict__ Knew,
                  const float* __restrict__ Vnew, const float* __restrict__ Kc,
                  const float* __restrict__ Vc, float* __restrict__ ws) {
    const int c = blockIdx.x, b = blockIdx.y, t = threadIdx.x;
    if (c == NSPLIT - 1)
        attn_body<NSPLIT, true >(c, b, t, Q, Knew, Vnew, Kc, Vc, ws);
    else
        attn_body<NSPLIT, false>(c, b, t, Q, Knew, Vnew, Kc, Vc, ws);
}

// ---------------------------------------------------------------------------
// Kernel 2: merge NC chunk partials + sink. grid = (KVH, BATCH), 256 threads.
// Two interleaved online-merge chains (even/odd chunks) to halve serial latency.
// ---------------------------------------------------------------------------
template <int NC>
__global__ __launch_bounds__(256)
void attn_combine(const float* __restrict__ ws, const float* __restrict__ sinks,
                  float* __restrict__ out) {
    const int kvh = blockIdx.x, b = blockIdx.y, t = threadIdx.x;
    const int h = t >> 5, lp = t & 31;
    const float* base = ws + (size_t)(b * KVH + kvh) * NC * REC_FLOATS;

    float M0 = -INFINITY, d0 = 0.f, M1 = -INFINITY, d1 = 0.f;
    float4 o0 = make_float4(0.f, 0.f, 0.f, 0.f);
    float4 o1 = make_float4(0.f, 0.f, 0.f, 0.f);

    #pragma unroll 2
    for (int cc = 0; cc < NC; cc += 2) {
        {
            const float* rec = base + (size_t)cc * REC_FLOATS;
            float mc = rec[h], lc = rec[QM + h];
            float4 a = *reinterpret_cast<const float4*>(rec + 2*QM + h*HD + 4*lp);
            float Mn = fmaxf(M0, mc);
            float fo = __expf(M0 - Mn), fc = __expf(mc - Mn);
            d0 = d0 * fo + fc * lc;
            o0.x = o0.x*fo + fc*a.x; o0.y = o0.y*fo + fc*a.y;
            o0.z = o0.z*fo + fc*a.z; o0.w = o0.w*fo + fc*a.w;
            M0 = Mn;
        }
        {
            const float* rec = base + (size_t)(cc + 1) * REC_FLOATS;
            float mc = rec[h], lc = rec[QM + h];
            float4 a = *reinterpret_cast<const float4*>(rec + 2*QM + h*HD + 4*lp);
            float Mn = fmaxf(M1, mc);
            float fo = __expf(M1 - Mn), fc = __expf(mc - Mn);
            d1 = d1 * fo + fc * lc;
            o1.x = o1.x*fo + fc*a.x; o1.y = o1.y*fo + fc*a.y;
            o1.z = o1.z*fo + fc*a.z; o1.w = o1.w*fo + fc*a.w;
            M1 = Mn;
        }
    }

    const float sk = sinks[kvh * QM + h];
    float M = fmaxf(fmaxf(M0, M1), sk);
    float f0 = __expf(M0 - M), f1 = __expf(M1 - M);
    float d = d0 * f0 + d1 * f1 + __expf(sk - M);   // sink: denominator only
    float inv = 1.f / d;
    float4 r;
    r.x = (o0.x*f0 + o1.x*f1) * inv;
    r.y = (o0.y*f0 + o1.y*f1) * inv;
    r.z = (o0.z*f0 + o1.z*f1) * inv;
    r.w = (o0.w*f0 + o1.w*f1) * inv;
    float* op = out + (size_t)b * NH * HD + (size_t)(kvh * QM + h) * HD + 4 * lp;
    *reinterpret_cast<float4*>(op) = r;
}

// ---------------------------------------------------------------------------
template <int NSPLIT>
static void launch_nc(const float* Q, const float* K, const float* V,
                      const float* Kc, const float* Vc, const float* sinks,
                      float* out, float* ws, hipStream_t stream) {
    dim3 g1(NSPLIT, BATCH);
    attn_partial<NSPLIT><<<g1, 256, 0, stream>>>(Q, K, V, Kc, Vc, ws);
    dim3 g2(KVH, BATCH);
    attn_combine<NSPLIT><<<g2, 256, 0, stream>>>(ws, sinks, out);
}

extern "C" void kernel_launch(void* const* d_in, const int* in_sizes, int n_in,
                              void* d_out, int out_size, void* d_ws, size_t ws_size,
                              hipStream_t stream) {
    const float* Q     = (const float*)d_in[0];
    const float* K     = (const float*)d_in[1];
    const float* V     = (const float*)d_in[2];
    const float* Kc    = (const float*)d_in[3];
    const float* Vc    = (const float*)d_in[4];
    const float* sinks = (const float*)d_in[5];
    float* out = (float*)d_out;
    float* ws  = (float*)d_ws;

    auto need = [](int nc) {
        return (size_t)BATCH * KVH * nc * REC_FLOATS * sizeof(float);
    };
    if (ws_size >= need(64))      launch_nc<64>(Q, K, V, Kc, Vc, sinks, out, ws, stream);
    else if (ws_size >= need(32)) launch_nc<32>(Q, K, V, Kc, Vc, sinks, out, ws, stream);
    else                          launch_nc<16>(Q, K, V, Kc, Vc, sinks, out, ws, stream);
}

// Round 5
// 121.421 us; speedup vs baseline: 1.2786x; 1.0049x over previous
//
#include <hip/hip_runtime.h>
#include <math.h>

#define BATCH 16
#define KVH 8
#define QM 8
#define NH 64
#define HD 128
#define CACHE 8192
#define WIN 4096
#define PSTART (CACHE + 1 - WIN)       // 4097: first unmasked position
#define KSTRIDE (KVH * HD)             // 1024 floats = 4 KB per cache row
#define REC_FLOATS (2 * QM + QM * HD)  // m[8], l[8], acc[8][128] = 1040
#define SM_SCALE 0.08838834764831845f

// broadcast lane h (imm = h<<5) to all lanes within each 32-lane half
#define BCAST(x, imm) __int_as_float(__builtin_amdgcn_ds_swizzle(__float_as_int(x), (imm)))

#define SCALE_ACC(h, rr) { acc[h].x *= rr; acc[h].y *= rr; acc[h].z *= rr; acc[h].w *= rr; }
#define PV_ACC(h, ww)    { acc[h].x += ww*vc4.x; acc[h].y += ww*vc4.y; acc[h].z += ww*vc4.z; acc[h].w += ww*vc4.w; }

// ---------------------------------------------------------------------------
// Kernel 1 (UNCHANGED from round 4 — verified): block = (batch b, span c),
// 256 threads cover the FULL 4 KB K/V row per position. Fully sequential
// 4 KB-row streams from HBM; no LDS storage; no barriers.
// ---------------------------------------------------------------------------
template <int NSPLIT, bool EDGE>
__device__ __forceinline__ void attn_body(
    int c, int b, int t,
    const float* __restrict__ Q, const float* __restrict__ Knew,
    const float* __restrict__ Vnew, const float* __restrict__ Kc,
    const float* __restrict__ Vc, float* __restrict__ ws) {
    constexpr int SPAN = WIN / NSPLIT;
    static_assert(SPAN % 2 == 0, "unroll-2");
    const int g  = t >> 5;     // kvh group
    const int dp = t & 31;     // lane in group
    const int pb = PSTART + c * SPAN;

    // Q fragment: 8 q-heads of kvh g, this lane's 4 dims (pre-scaled)
    float4 q4[8];
    {
        const float* qp = Q + ((size_t)b * NH + (size_t)g * QM) * HD + dp * 4;
        #pragma unroll
        for (int h = 0; h < 8; ++h) {
            float4 v = *reinterpret_cast<const float4*>(qp + h * HD);
            q4[h] = make_float4(v.x * SM_SCALE, v.y * SM_SCALE,
                                v.z * SM_SCALE, v.w * SM_SCALE);
        }
    }

    const float* kb_ = Kc + ((size_t)b * CACHE + pb) * KSTRIDE + t * 4;
    const float* vb_ = Vc + ((size_t)b * CACHE + pb) * KSTRIDE + t * 4;
    const float* kn_ = Knew + (size_t)b * KSTRIDE + t * 4;
    const float* vn_ = Vnew + (size_t)b * KSTRIDE + t * 4;

    auto LK = [&](int j) -> float4 {
        const float* a = kb_ + (size_t)j * KSTRIDE;
        if (EDGE && (pb + j >= CACHE)) a = kn_;   // folds away for !EDGE
        return *reinterpret_cast<const float4*>(a);
    };
    auto LV = [&](int j) -> float4 {
        const float* a = vb_ + (size_t)j * KSTRIDE;
        if (EDGE && (pb + j >= CACHE)) a = vn_;
        return *reinterpret_cast<const float4*>(a);
    };

    float4 acc[8];
    #pragma unroll
    for (int h = 0; h < 8; ++h) acc[h] = make_float4(0.f, 0.f, 0.f, 0.f);
    float mrun = -INFINITY, lrun = 0.f;

    auto STEP = [&](float4 kc4, float4 vc4) {
        // partial dots: 8 heads x this lane's 4 dims
        float p0 = q4[0].x*kc4.x + q4[0].y*kc4.y + q4[0].z*kc4.z + q4[0].w*kc4.w;
        float p1 = q4[1].x*kc4.x + q4[1].y*kc4.y + q4[1].z*kc4.z + q4[1].w*kc4.w;
        float p2 = q4[2].x*kc4.x + q4[2].y*kc4.y + q4[2].z*kc4.z + q4[2].w*kc4.w;
        float p3 = q4[3].x*kc4.x + q4[3].y*kc4.y + q4[3].z*kc4.z + q4[3].w*kc4.w;
        float p4 = q4[4].x*kc4.x + q4[4].y*kc4.y + q4[4].z*kc4.z + q4[4].w*kc4.w;
        float p5 = q4[5].x*kc4.x + q4[5].y*kc4.y + q4[5].z*kc4.z + q4[5].w*kc4.w;
        float p6 = q4[6].x*kc4.x + q4[6].y*kc4.y + q4[6].z*kc4.z + q4[6].w*kc4.w;
        float p7 = q4[7].x*kc4.x + q4[7].y*kc4.y + q4[7].z*kc4.z + q4[7].w*kc4.w;
        // fold head-bit0 via lane-bit0
        const bool s1 = dp & 1;
        float a0 = (s1?p1:p0) + __shfl_xor((s1?p0:p1), 1);
        float a1 = (s1?p3:p2) + __shfl_xor((s1?p2:p3), 1);
        float a2 = (s1?p5:p4) + __shfl_xor((s1?p4:p5), 1);
        float a3 = (s1?p7:p6) + __shfl_xor((s1?p6:p7), 1);
        // fold head-bit1 via lane-bit1
        const bool s2 = dp & 2;
        float b0 = (s2?a1:a0) + __shfl_xor((s2?a0:a1), 2);
        float b1 = (s2?a3:a2) + __shfl_xor((s2?a2:a3), 2);
        // fold head-bit2 via lane-bit2
        const bool s4 = dp & 4;
        float s = (s4?b1:b0) + __shfl_xor((s4?b0:b1), 4);
        // spatial butterfly -> full 128-dim dot, head = dp&7, replicated x4
        s += __shfl_xor(s, 8);
        s += __shfl_xor(s, 16);

        // deferred-max online softmax (rescale only when max grows > 8)
        if (__any(s > mrun + 8.0f)) {
            float mn = fmaxf(mrun, s);
            float rs = __expf(mrun - mn);   // 0 on first step
            mrun = mn; lrun *= rs;
            float r0 = BCAST(rs, 0x00); SCALE_ACC(0, r0);
            float r1 = BCAST(rs, 0x20); SCALE_ACC(1, r1);
            float r2 = BCAST(rs, 0x40); SCALE_ACC(2, r2);
            float r3 = BCAST(rs, 0x60); SCALE_ACC(3, r3);
            float r4 = BCAST(rs, 0x80); SCALE_ACC(4, r4);
            float r5 = BCAST(rs, 0xA0); SCALE_ACC(5, r5);
            float r6 = BCAST(rs, 0xC0); SCALE_ACC(6, r6);
            float r7 = BCAST(rs, 0xE0); SCALE_ACC(7, r7);
        }
        float e = __expf(s - mrun);
        lrun += e;
        float w0 = BCAST(e, 0x00); PV_ACC(0, w0);
        float w1 = BCAST(e, 0x20); PV_ACC(1, w1);
        float w2 = BCAST(e, 0x40); PV_ACC(2, w2);
        float w3 = BCAST(e, 0x60); PV_ACC(3, w3);
        float w4 = BCAST(e, 0x80); PV_ACC(4, w4);
        float w5 = BCAST(e, 0xA0); PV_ACC(5, w5);
        float w6 = BCAST(e, 0xC0); PV_ACC(6, w6);
        float w7 = BCAST(e, 0xE0); PV_ACC(7, w7);
    };

    // depth-2 prefetch, unroll-2 (statically-named buffers)
    float4 ka = LK(0), va = LV(0), kb4 = LK(1), vb4 = LV(1);
    for (int j = 0; j < SPAN; j += 2) {
        float4 k0 = ka, v0 = va;
        ka = LK(j + 2); va = LV(j + 2);     // over-read past span is in-bounds
        STEP(k0, v0);
        float4 k1 = kb4, v1 = vb4;
        kb4 = LK(j + 3); vb4 = LV(j + 3);
        STEP(k1, v1);
    }

    // write partial record for (b, kvh=g, chunk=c); lanes 0..7 hold heads 0..7
    float* rec = ws + ((size_t)(b * KVH + g) * NSPLIT + c) * REC_FLOATS;
    if (dp < 8) { rec[dp] = mrun; rec[QM + dp] = lrun; }
    #pragma unroll
    for (int h = 0; h < 8; ++h)
        *reinterpret_cast<float4*>(rec + 2 * QM + h * HD + dp * 4) = acc[h];
}

template <int NSPLIT>
__global__ __launch_bounds__(256, 4)
void attn_partial(const float* __restrict__ Q, const float* __restrict__ Knew,
                  const float* __restrict__ Vnew, const float* __restrict__ Kc,
                  const float* __restrict__ Vc, float* __restrict__ ws) {
    const int c = blockIdx.x, b = blockIdx.y, t = threadIdx.x;
    if (c == NSPLIT - 1)
        attn_body<NSPLIT, true >(c, b, t, Q, Knew, Vnew, Kc, Vc, ws);
    else
        attn_body<NSPLIT, false>(c, b, t, Q, Knew, Vnew, Kc, Vc, ws);
}

// ---------------------------------------------------------------------------
// Kernel 2 (NEW): parallel two-phase combine.
// grid = (KVH, BATCH, DSPLIT=4), block = 256.
// Phase A (redundant per z-slice, cheap): head h = t>>5, lane lc = t&31 loads
//   (m,l) for chunks lc (+lc+32 if NC==64); shuffle-reduce max (incl. sink)
//   and denominator; deposit normalized weight w[h][c] = exp(m_c-M)/denom in
//   LDS (padded stride 65 -> conflict-free across h).
// Phase B: slot = (head, quad) with quad = 8*ds + (t&7); 4-way chunk parity
//   (par = t>>6); each thread: NC/4 independent float4 loads+FMA; LDS fold;
//   threads 0..63 write coalesced float4 to out.
// ---------------------------------------------------------------------------
template <int NC>
__global__ __launch_bounds__(256)
void attn_combine(const float* __restrict__ ws, const float* __restrict__ sinks,
                  float* __restrict__ out) {
    static_assert(NC == 32 || NC == 64, "NC");
    const int kvh = blockIdx.x, b = blockIdx.y, ds = blockIdx.z;
    const int t = threadIdx.x;
    const float* base = ws + (size_t)(b * KVH + kvh) * NC * REC_FLOATS;

    __shared__ float  wlds[QM][65];     // padded: bank = (h + c) & 31
    __shared__ float4 plds[4][64];

    // ---- Phase A ----
    {
        const int h = t >> 5, lc = t & 31;
        const float sk = sinks[kvh * QM + h];
        float m0 = base[(size_t)lc * REC_FLOATS + h];
        float l0 = base[(size_t)lc * REC_FLOATS + QM + h];
        float m1 = -INFINITY, l1 = 0.f;
        if constexpr (NC == 64) {
            m1 = base[(size_t)(lc + 32) * REC_FLOATS + h];
            l1 = base[(size_t)(lc + 32) * REC_FLOATS + QM + h];
        }
        float M = fmaxf(fmaxf(m0, m1), sk);
        #pragma unroll
        for (int off = 16; off; off >>= 1) M = fmaxf(M, __shfl_xor(M, off));
        float f0 = __expf(m0 - M);
        float f1 = (NC == 64) ? __expf(m1 - M) : 0.f;
        float dsum = f0 * l0 + f1 * l1;
        #pragma unroll
        for (int off = 16; off; off >>= 1) dsum += __shfl_xor(dsum, off);
        float inv = 1.f / (dsum + __expf(sk - M));   // sink: denominator only
        wlds[h][lc] = f0 * inv;
        if constexpr (NC == 64) wlds[h][lc + 32] = f1 * inv;
    }
    __syncthreads();

    // ---- Phase B ----
    const int qd  = (t & 7) + 8 * ds;    // dim quad 0..31
    const int h   = (t >> 3) & 7;
    const int par = t >> 6;              // 0..3
    float4 o = make_float4(0.f, 0.f, 0.f, 0.f);
    #pragma unroll 4
    for (int c = par; c < NC; c += 4) {
        float w = wlds[h][c];
        const float* ap = base + (size_t)c * REC_FLOATS + 2 * QM + h * HD + 4 * qd;
        float4 a = *reinterpret_cast<const float4*>(ap);
        o.x += w * a.x; o.y += w * a.y; o.z += w * a.z; o.w += w * a.w;
    }
    plds[par][t & 63] = o;
    __syncthreads();
    if (t < 64) {
        float4 r0 = plds[0][t], r1 = plds[1][t], r2 = plds[2][t], r3 = plds[3][t];
        float4 r;
        r.x = (r0.x + r1.x) + (r2.x + r3.x);
        r.y = (r0.y + r1.y) + (r2.y + r3.y);
        r.z = (r0.z + r1.z) + (r2.z + r3.z);
        r.w = (r0.w + r1.w) + (r2.w + r3.w);
        const int hh = (t >> 3) & 7, qq = (t & 7) + 8 * ds;
        float* op = out + (size_t)b * NH * HD + (size_t)(kvh * QM + hh) * HD + 4 * qq;
        *reinterpret_cast<float4*>(op) = r;
    }
}

// ---------------------------------------------------------------------------
template <int NSPLIT>
static void launch_nc(const float* Q, const float* K, const float* V,
                      const float* Kc, const float* Vc, const float* sinks,
                      float* out, float* ws, hipStream_t stream) {
    dim3 g1(NSPLIT, BATCH);
    attn_partial<NSPLIT><<<g1, 256, 0, stream>>>(Q, K, V, Kc, Vc, ws);
    dim3 g2(KVH, BATCH, 4);
    attn_combine<NSPLIT><<<g2, 256, 0, stream>>>(ws, sinks, out);
}

extern "C" void kernel_launch(void* const* d_in, const int* in_sizes, int n_in,
                              void* d_out, int out_size, void* d_ws, size_t ws_size,
                              hipStream_t stream) {
    const float* Q     = (const float*)d_in[0];
    const float* K     = (const float*)d_in[1];
    const float* V     = (const float*)d_in[2];
    const float* Kc    = (const float*)d_in[3];
    const float* Vc    = (const float*)d_in[4];
    const float* sinks = (const float*)d_in[5];
    float* out = (float*)d_out;
    float* ws  = (float*)d_ws;

    auto need = [](int nc) {
        return (size_t)BATCH * KVH * nc * REC_FLOATS * sizeof(float);
    };
    if (ws_size >= need(64)) launch_nc<64>(Q, K, V, Kc, Vc, sinks, out, ws, stream);
    else                     launch_nc<32>(Q, K, V, Kc, Vc, sinks, out, ws, stream);
}